// Round 13
// baseline (274.011 us; speedup 1.0000x reference)
//
#include <hip/hip_runtime.h>

// z_i = mu[a_i] + tril(cov[a_i]) @ eps_i   (B=4194304, A=64, D=8)
//
// History:
//  R4  (44x b32 LDS gather):  89.2us, 2.4TB/s, conflicts 5.8M, VALU 7.5%
//  R7  (128B lane stride):   387us — 1 line per lane per instr (+nt)
//  R8  (grid-stride ILP x4):  97.5us — ILP null
//  R9  (14x b128 gather):     86.8us — LDS instr count null
//  R12 (shuffle gather):      95.6us — compiled back to R4 pattern, null
// All share: 32B/row accessed as 2x16B instrs with 32B inter-lane stride ->
// each VMEM instr touches 32 lines (32B useful/line); stores hit L2 as 2
// partial-line transactions per 64B line. Request count per instr tracks dur
// across R7/R4 almost linearly -> v6 makes every eps/out instruction
// lane-contiguous (16 lines/instr, full 64B per line):
//  - wave processes 64 contiguous rows (2KB) per iter; lane l loads chunk l
//    and chunk 64+l (both instrs contiguous 1KB).
//  - adjacent lane pairs exchange 16B halves via DPP quad_perm[1,0,3,2]
//    (VALU pipe, NOT __shfl which lowers to LDS ds_bpermute).
//  - even lane computes row base+(l>>1), odd lane row base+32+(l>>1).
//  - stores mirrored. Table gather unchanged from R4 (single-variable test).

#define THREADS 256
#define A_CNT 64
#define L_STRIDE 65   // 64 + 1 pad: bank = (a + k) % 32
#define MU_STRIDE 9

__device__ __forceinline__ float dpp_swap1(float x) {
    // v_mov_b32_dpp quad_perm:[1,0,3,2] — swap adjacent lanes, VALU pipe.
    return __int_as_float(
        __builtin_amdgcn_mov_dpp(__float_as_int(x), 0xB1, 0xF, 0xF, false));
}
__device__ __forceinline__ float4 dpp_swap1_f4(float4 v) {
    return make_float4(dpp_swap1(v.x), dpp_swap1(v.y),
                       dpp_swap1(v.z), dpp_swap1(v.w));
}

__global__ __launch_bounds__(THREADS) void latent_rsample_v6(
    const int* __restrict__ annot,
    const float* __restrict__ eps,
    const float* __restrict__ mu,
    const float* __restrict__ cov,
    float* __restrict__ out,
    int B)
{
    __shared__ float L_lds[A_CNT * L_STRIDE];
    __shared__ float mu_lds[A_CNT * MU_STRIDE];

    for (int e = threadIdx.x; e < A_CNT * 64; e += THREADS) {
        int a  = e >> 6;
        int rc = e & 63;
        L_lds[a * L_STRIDE + rc] = cov[e];
    }
    for (int e = threadIdx.x; e < A_CNT * 8; e += THREADS) {
        int a = e >> 3;
        int r = e & 7;
        mu_lds[a * MU_STRIDE + r] = mu[e];
    }
    __syncthreads();

    const int lane = threadIdx.x & 63;
    const int gw   = blockIdx.x * (THREADS / 64) + (threadIdx.x >> 6);
    const int nW   = gridDim.x * (THREADS / 64);
    const bool ev  = !(lane & 1);

    for (int bw = gw; (long)bw * 64 < B; bw += nW) {
        const int base = bw * 64;                 // this wave's 64-row block

        if (base + 64 <= B) {
            // ---- fast path: fully contiguous I/O ----
            const int myrow = base + ((lane & 1) << 5) + (lane >> 1);
            const int a = annot[myrow];

            const float4* blk =
                reinterpret_cast<const float4*>(eps + (size_t)base * 8);
            const float4 EA = blk[lane];          // chunk l        (1KB contig)
            const float4 EB = blk[64 + lane];     // chunk 64+l     (1KB contig)
            const float4 XA = dpp_swap1_f4(EA);   // partner's chunk
            const float4 XB = dpp_swap1_f4(EB);

            // even lane: row base+(l>>1)   = {EA, XA}
            // odd  lane: row base+32+(l>>1)= {XB, EB}
            const float4 elo = ev ? EA : XB;
            const float4 ehi = ev ? XA : EB;
            const float ef[8] = {elo.x, elo.y, elo.z, elo.w,
                                 ehi.x, ehi.y, ehi.z, ehi.w};

            const float* __restrict__ Lr = &L_lds[a * L_STRIDE];
            const float* __restrict__ mr = &mu_lds[a * MU_STRIDE];

            float z[8];
            #pragma unroll
            for (int r = 0; r < 8; ++r) {
                float acc = mr[r];
                #pragma unroll
                for (int c = 0; c <= r; ++c)      // tril
                    acc += Lr[r * 8 + c] * ef[c];
                z[r] = acc;
            }

            const float4 zlo = make_float4(z[0], z[1], z[2], z[3]);
            const float4 zhi = make_float4(z[4], z[5], z[6], z[7]);
            const float4 Y1 = dpp_swap1_f4(zhi);  // odd gets even's zhi
            const float4 Y2 = dpp_swap1_f4(zlo);  // even gets odd's zlo

            float4* blkO = reinterpret_cast<float4*>(out + (size_t)base * 8);
            blkO[lane]      = ev ? zlo : Y1;      // chunks 0..63   (contig)
            blkO[64 + lane] = ev ? Y2  : zhi;     // chunks 64..127 (contig)
        } else {
            // ---- tail (unused for B=2^22): per-row guarded, R4-style ----
            const int i = base + lane;
            if (i < B) {
                const int a = annot[i];
                const float* __restrict__ Lr = &L_lds[a * L_STRIDE];
                const float* __restrict__ mr = &mu_lds[a * MU_STRIDE];
                const float4* ep =
                    reinterpret_cast<const float4*>(eps + (size_t)i * 8);
                const float4 ea = ep[0];
                const float4 eb = ep[1];
                const float ef[8] = {ea.x, ea.y, ea.z, ea.w,
                                     eb.x, eb.y, eb.z, eb.w};
                float z[8];
                #pragma unroll
                for (int r = 0; r < 8; ++r) {
                    float acc = mr[r];
                    #pragma unroll
                    for (int c = 0; c <= r; ++c) acc += Lr[r * 8 + c] * ef[c];
                    z[r] = acc;
                }
                float4* op = reinterpret_cast<float4*>(out + (size_t)i * 8);
                op[0] = make_float4(z[0], z[1], z[2], z[3]);
                op[1] = make_float4(z[4], z[5], z[6], z[7]);
            }
        }
    }
}

extern "C" void kernel_launch(void* const* d_in, const int* in_sizes, int n_in,
                              void* d_out, int out_size, void* d_ws, size_t ws_size,
                              hipStream_t stream) {
    const int*   annot = (const int*)  d_in[0];   // [B] int32
    const float* eps   = (const float*)d_in[1];   // [B, 8] f32
    const float* mu    = (const float*)d_in[2];   // [64, 8] f32
    const float* cov   = (const float*)d_in[3];   // [64, 8, 8] f32
    float* out = (float*)d_out;                   // [B, 8] f32

    const int B = in_sizes[0];                    // 4194304
    const int blocks = 2048;                      // 8192 waves, 8 iters each

    latent_rsample_v6<<<blocks, THREADS, 0, stream>>>(annot, eps, mu, cov, out, B);
}